// Round 9
// baseline (292.490 us; speedup 1.0000x reference)
//
#include <hip/hip_runtime.h>

#define BATCH 2
#define SEQ   4096
#define HID   256
#define NHEAD 8
#define DH    32
// defer-max threshold in log2 units (≈ 8 nats)
#define THR_L2 11.5f
// 1/sqrt(32) * log2(e)
#define QSCALE 0.25501639769925074f
// -(1/10) * log2(e)
#define BIASC (-0.14426950408889634f)

typedef __attribute__((ext_vector_type(8))) _Float16 half8;
typedef __attribute__((ext_vector_type(4))) _Float16 half4;
typedef __attribute__((ext_vector_type(2))) __fp16   fp16x2;
typedef __attribute__((ext_vector_type(4))) float    f32x4;
typedef __attribute__((ext_vector_type(4))) unsigned int uint4v;

__device__ __forceinline__ float fast_exp2(float x) {
    return __builtin_amdgcn_exp2f(x);
}

// ---------------------------------------------------------------- convert
__global__ void cvt_f32_f16(const float* __restrict__ src,
                            _Float16* __restrict__ dst, int n) {
    int i = (blockIdx.x * blockDim.x + threadIdx.x) * 4;
    if (i >= n) return;
    f32x4 v = *reinterpret_cast<const f32x4*>(src + i);
    half4 h;
#pragma unroll
    for (int c = 0; c < 4; ++c) h[c] = (_Float16)v[c];
    *reinterpret_cast<half4*>(dst + i) = h;
}

__global__ void cvt_w4(const float* __restrict__ a, const float* __restrict__ b,
                       const float* __restrict__ c, const float* __restrict__ d,
                       _Float16* __restrict__ dst) {
    const float* srcs[4] = {a, b, c, d};
    const float* s = srcs[blockIdx.y];
    const int i = (blockIdx.x * blockDim.x + threadIdx.x) * 4;
    f32x4 v = *reinterpret_cast<const f32x4*>(s + i);
    half4 h;
#pragma unroll
    for (int k = 0; k < 4; ++k) h[k] = (_Float16)v[k];
    *reinterpret_cast<half4*>(dst + (size_t)blockIdx.y * HID * HID + i) = h;
}

// ---------------------------------------------------------------- paug
// Augmented position rows for the d2-MFMA: for global row j (over B*SEQ):
//   paug[j][0..7] = [-2x, -2y, -2z, |p|^2, 1, 0, 0, 0], rest zeros (k=8..31).
// d2[j][i] = paug[j][:] . qaug[i][:] with qaug = [x_i, y_i, z_i, 1, |p_i|^2].
__global__ void paug_kernel(const float* __restrict__ pos,
                            _Float16* __restrict__ Paug) {
    const int j = blockIdx.x * 256 + threadIdx.x;   // 0 .. B*SEQ-1
    const float* p = pos + (size_t)j * 3;
    const float x = p[0], y = p[1], z = p[2];
    half8 r0;
#pragma unroll
    for (int k = 0; k < 8; ++k) r0[k] = (_Float16)0.f;
    r0[0] = (_Float16)(-2.f * x);
    r0[1] = (_Float16)(-2.f * y);
    r0[2] = (_Float16)(-2.f * z);
    r0[3] = (_Float16)(x * x + y * y + z * z);
    r0[4] = (_Float16)1.f;
    half8 zz;
#pragma unroll
    for (int k = 0; k < 8; ++k) zz[k] = (_Float16)0.f;
    _Float16* dst = Paug + (size_t)j * 32;
    *reinterpret_cast<half8*>(dst)      = r0;
    *reinterpret_cast<half8*>(dst + 8)  = zz;
    *reinterpret_cast<half8*>(dst + 16) = zz;
    *reinterpret_cast<half8*>(dst + 24) = zz;
}

// ---------------------------------------------------------------- QKV proj
// V stored transposed [B][H][DH][SEQ] with a within-32 column permutation so
// that the QK^T output fragment, packed pairwise, is directly the PV
// A-fragment: col = (nn&~31) | ((nn&12)<<1) | ((nn&16)>>2) | (nn&3)
__global__ __launch_bounds__(256) void qkv_proj(
    const _Float16* __restrict__ xh, const _Float16* __restrict__ Wh,
    const float* __restrict__ bq, const float* __restrict__ bk,
    const float* __restrict__ bv,
    _Float16* __restrict__ Qh, _Float16* __restrict__ Kh,
    _Float16* __restrict__ Vt)
{
    const int z   = blockIdx.z;
    const int m0  = blockIdx.x * 64;
    const int n0  = blockIdx.y * 64;
    const int tid = threadIdx.x;
    const int w   = tid >> 6, lane = tid & 63;
    const int lr  = lane & 15, lg = lane >> 4;
    const int wr  = (w >> 1) * 32, wc = (w & 1) * 32;

    const _Float16* Wp = Wh + (size_t)z * HID * HID;
    const float* bias = (z == 0) ? bq : (z == 1) ? bk : bv;

    f32x4 acc[2][2] = {};
    const int ar = m0 + wr + lr;
    const int br = n0 + wc + lr;
#pragma unroll
    for (int ks = 0; ks < 8; ++ks) {
        const int ko = ks * 32 + lg * 8;
        half8 a0 = *reinterpret_cast<const half8*>(xh + (size_t)ar * HID + ko);
        half8 a1 = *reinterpret_cast<const half8*>(xh + (size_t)(ar + 16) * HID + ko);
        half8 b0 = *reinterpret_cast<const half8*>(Wp + (size_t)br * HID + ko);
        half8 b1 = *reinterpret_cast<const half8*>(Wp + (size_t)(br + 16) * HID + ko);
        acc[0][0] = __builtin_amdgcn_mfma_f32_16x16x32_f16(a0, b0, acc[0][0], 0, 0, 0);
        acc[0][1] = __builtin_amdgcn_mfma_f32_16x16x32_f16(a0, b1, acc[0][1], 0, 0, 0);
        acc[1][0] = __builtin_amdgcn_mfma_f32_16x16x32_f16(a1, b0, acc[1][0], 0, 0, 0);
        acc[1][1] = __builtin_amdgcn_mfma_f32_16x16x32_f16(a1, b1, acc[1][1], 0, 0, 0);
    }
#pragma unroll
    for (int mf = 0; mf < 2; ++mf)
#pragma unroll
    for (int nf = 0; nf < 2; ++nf)
#pragma unroll
    for (int r = 0; r < 4; ++r) {
        const int m  = m0 + wr + mf * 16 + lg * 4 + r;
        const int o  = n0 + wc + nf * 16 + lr;
        const int bb = m >> 12, nn = m & (SEQ - 1);
        const int hh = o >> 5,  dd = o & (DH - 1);
        float v = acc[mf][nf][r] + bias[o];
        if (z == 0) {
            Qh[(((size_t)(bb * NHEAD + hh) * SEQ) + nn) * DH + dd] =
                (_Float16)(v * QSCALE);
        } else if (z == 1) {
            Kh[(((size_t)(bb * NHEAD + hh) * SEQ) + nn) * DH + dd] = (_Float16)v;
        } else {
            const int pp = (nn & ~31) | ((nn & 12) << 1) | ((nn & 16) >> 2) | (nn & 3);
            Vt[(((size_t)(bb * NHEAD + hh) * DH) + dd) * SEQ + pp] = (_Float16)v;
        }
    }
}

// ---------------------------------------------------------------- attention
// One 64-key tile. Manual counted-vmcnt pipeline: this tile issues
// PG(t) [4], V(t) [4], K(t+1) [4]; entering pending = K(t) [4].
// FIFO: K(t) | PG(t) | V(t) | K(t+1)  ->  waits vmcnt(12)/(8)/(4).
__device__ __forceinline__ void attn_tile(
    half8 (&kc)[4], half8 (&kn)[4],
    unsigned long long& ka, unsigned long long& pa,
    unsigned long long& va0, unsigned long long& va1,
    half8 aq, half8 qaug, float* xw,
    float& mrun, float& lsum, f32x4& acc0, f32x4& acc1, int lane, int lg)
{
    half8 pg0, pg1, pg2, pg3, vc0, vc1, vc2, vc3;
    asm volatile(
        "global_load_dwordx4 %0, %[pa], off\n\t"
        "global_load_dwordx4 %1, %[pa], off offset:1024\n\t"
        "global_load_dwordx4 %2, %[pa], off offset:2048\n\t"
        "global_load_dwordx4 %3, %[pa], off offset:3072\n\t"
        "global_load_dwordx4 %4, %[va0], off\n\t"
        "global_load_dwordx4 %5, %[va1], off\n\t"
        "global_load_dwordx4 %6, %[va0], off offset:64\n\t"
        "global_load_dwordx4 %7, %[va1], off offset:64\n\t"
        "global_load_dwordx4 %8, %[ka], off\n\t"
        "global_load_dwordx4 %9, %[ka], off offset:1024\n\t"
        "global_load_dwordx4 %10, %[ka], off offset:2048\n\t"
        "global_load_dwordx4 %11, %[ka], off offset:3072"
        : "=&v"(pg0), "=&v"(pg1), "=&v"(pg2), "=&v"(pg3),
          "=&v"(vc0), "=&v"(vc1), "=&v"(vc2), "=&v"(vc3),
          "=&v"(kn[0]), "=&v"(kn[1]), "=&v"(kn[2]), "=&v"(kn[3])
        : [pa]"v"(pa), [va0]"v"(va0), [va1]"v"(va1), [ka]"v"(ka));
    pa += 4096; va0 += 128; va1 += 128; ka += 4096;

    // ---- K(t) ready
    asm volatile("s_waitcnt vmcnt(12)");
    __builtin_amdgcn_sched_barrier(0);
    f32x4 z4 = {0.f, 0.f, 0.f, 0.f};
    f32x4 vv[4];
    __builtin_amdgcn_s_setprio(1);
    vv[0] = __builtin_amdgcn_mfma_f32_16x16x32_f16(kc[0], aq, z4, 0, 0, 0);
    vv[1] = __builtin_amdgcn_mfma_f32_16x16x32_f16(kc[1], aq, z4, 0, 0, 0);
    vv[2] = __builtin_amdgcn_mfma_f32_16x16x32_f16(kc[2], aq, z4, 0, 0, 0);
    vv[3] = __builtin_amdgcn_mfma_f32_16x16x32_f16(kc[3], aq, z4, 0, 0, 0);
    __builtin_amdgcn_s_setprio(0);

    // ---- PG(t) ready -> d2 fragments, fold bias into vv
    asm volatile("s_waitcnt vmcnt(8)");
    __builtin_amdgcn_sched_barrier(0);
    f32x4 dd[4];
    dd[0] = __builtin_amdgcn_mfma_f32_16x16x32_f16(pg0, qaug, z4, 0, 0, 0);
    dd[1] = __builtin_amdgcn_mfma_f32_16x16x32_f16(pg1, qaug, z4, 0, 0, 0);
    dd[2] = __builtin_amdgcn_mfma_f32_16x16x32_f16(pg2, qaug, z4, 0, 0, 0);
    dd[3] = __builtin_amdgcn_mfma_f32_16x16x32_f16(pg3, qaug, z4, 0, 0, 0);
#pragma unroll
    for (int cf = 0; cf < 4; ++cf)
#pragma unroll
    for (int t = 0; t < 4; ++t)
        vv[cf][t] += BIASC * sqrtf(fmaxf(dd[cf][t], 0.f));

    // ---- lane-local defer-max online softmax (log2 domain)
    float m0 = fmaxf(fmaxf(vv[0][0], vv[0][1]), vv[0][2]);
    float m1 = fmaxf(fmaxf(vv[0][3], vv[1][0]), vv[1][1]);
    float m2 = fmaxf(fmaxf(vv[1][2], vv[1][3]), vv[2][0]);
    float m3 = fmaxf(fmaxf(vv[2][1], vv[2][2]), vv[2][3]);
    float m4 = fmaxf(fmaxf(vv[3][0], vv[3][1]), vv[3][2]);
    float tmax = fmaxf(fmaxf(fmaxf(m0, m1), fmaxf(m2, m3)),
                       fmaxf(m4, vv[3][3]));

    if (!__all(tmax <= mrun + THR_L2)) {     // rare rescale path (wave-uniform)
        float tm = tmax;
        tm = fmaxf(tm, __shfl_xor(tm, 16, 64));
        tm = fmaxf(tm, __shfl_xor(tm, 32, 64));
        const float mnew  = fmaxf(mrun, tm);
        const float alpha = fast_exp2(mrun - mnew);
        if (lane < 16) xw[lane] = alpha;
        f32x4 a4 = *reinterpret_cast<const f32x4*>(&xw[lg * 4]);
        lsum *= alpha;
        mrun = mnew;
        acc0 *= a4;
        acc1 *= a4;
    }

    // ---- exp2 + pairwise pack straight into the PV A-fragments
    float e00 = fast_exp2(vv[0][0] - mrun), e01 = fast_exp2(vv[0][1] - mrun);
    float e02 = fast_exp2(vv[0][2] - mrun), e03 = fast_exp2(vv[0][3] - mrun);
    float e10 = fast_exp2(vv[1][0] - mrun), e11 = fast_exp2(vv[1][1] - mrun);
    float e12 = fast_exp2(vv[1][2] - mrun), e13 = fast_exp2(vv[1][3] - mrun);
    float e20 = fast_exp2(vv[2][0] - mrun), e21 = fast_exp2(vv[2][1] - mrun);
    float e22 = fast_exp2(vv[2][2] - mrun), e23 = fast_exp2(vv[2][3] - mrun);
    float e30 = fast_exp2(vv[3][0] - mrun), e31 = fast_exp2(vv[3][1] - mrun);
    float e32 = fast_exp2(vv[3][2] - mrun), e33 = fast_exp2(vv[3][3] - mrun);
    lsum += ((e00 + e01) + (e02 + e03)) + ((e10 + e11) + (e12 + e13)) +
            ((e20 + e21) + (e22 + e23)) + ((e30 + e31) + (e32 + e33));

    uint4v u0, u1;
    u0[0] = __builtin_bit_cast(unsigned int, __builtin_amdgcn_cvt_pkrtz(e00, e01));
    u0[1] = __builtin_bit_cast(unsigned int, __builtin_amdgcn_cvt_pkrtz(e02, e03));
    u0[2] = __builtin_bit_cast(unsigned int, __builtin_amdgcn_cvt_pkrtz(e10, e11));
    u0[3] = __builtin_bit_cast(unsigned int, __builtin_amdgcn_cvt_pkrtz(e12, e13));
    u1[0] = __builtin_bit_cast(unsigned int, __builtin_amdgcn_cvt_pkrtz(e20, e21));
    u1[1] = __builtin_bit_cast(unsigned int, __builtin_amdgcn_cvt_pkrtz(e22, e23));
    u1[2] = __builtin_bit_cast(unsigned int, __builtin_amdgcn_cvt_pkrtz(e30, e31));
    u1[3] = __builtin_bit_cast(unsigned int, __builtin_amdgcn_cvt_pkrtz(e32, e33));
    half8 pa0 = __builtin_bit_cast(half8, u0);
    half8 pa1 = __builtin_bit_cast(half8, u1);

    // ---- V(t) ready -> PV (V cols pre-permuted to match the pack)
    asm volatile("s_waitcnt vmcnt(4)");
    __builtin_amdgcn_sched_barrier(0);
    __builtin_amdgcn_s_setprio(1);
    acc0 = __builtin_amdgcn_mfma_f32_16x16x32_f16(pa0, vc0, acc0, 0, 0, 0);
    acc1 = __builtin_amdgcn_mfma_f32_16x16x32_f16(pa0, vc1, acc1, 0, 0, 0);
    acc0 = __builtin_amdgcn_mfma_f32_16x16x32_f16(pa1, vc2, acc0, 0, 0, 0);
    acc1 = __builtin_amdgcn_mfma_f32_16x16x32_f16(pa1, vc3, acc1, 0, 0, 0);
    __builtin_amdgcn_s_setprio(0);
}

// grid = 4096 one-wave blocks. g&15 -> (b,h) so each XCD serves ~2 K/V
// streams (L2-resident); g>>4 -> i-block. No barriers, no bulk LDS.
__global__ __launch_bounds__(64, 4) void attn_kernel(
    const _Float16* __restrict__ Qh, const _Float16* __restrict__ Kh,
    const _Float16* __restrict__ Vt, const _Float16* __restrict__ Paug,
    const float* __restrict__ pos, _Float16* __restrict__ AO)
{
    __shared__ float xw[16];

    const int g    = blockIdx.x;
    const int bh   = g & 15;
    const int iblk = g >> 4;
    const int b    = bh >> 3, h = bh & 7;
    const int i0   = iblk * 16;
    const int lane = threadIdx.x;
    const int lr   = lane & 15, lg = lane >> 4;

    const size_t bhh = (size_t)(b * NHEAD + h);
    const half8 aq = *reinterpret_cast<const half8*>(
        Qh + (bhh * SEQ + i0 + lr) * DH + lg * 8);

    // qaug: lg==0 k-slice = [x_i, y_i, z_i, 1, |p_i|^2, 0,0,0]; else zeros
    const float* pp = pos + (size_t)(b * SEQ + i0 + lr) * 3;
    const float px = pp[0], py = pp[1], pz = pp[2];
    half8 qaug;
#pragma unroll
    for (int k = 0; k < 8; ++k) qaug[k] = (_Float16)0.f;
    if (lg == 0) {
        qaug[0] = (_Float16)px;
        qaug[1] = (_Float16)py;
        qaug[2] = (_Float16)pz;
        qaug[3] = (_Float16)1.f;
        qaug[4] = (_Float16)(px * px + py * py + pz * pz);
    }
    // pin: force aq/qaug materialized (and their waits) before the pipeline
    asm volatile("" :: "v"(aq), "v"(qaug));

    unsigned long long ka  = (unsigned long long)(Kh + bhh * SEQ * DH +
                                                  (size_t)lr * DH + lg * 8);
    unsigned long long pa  = (unsigned long long)(Paug +
                                 ((size_t)b * SEQ + lr) * 32 + lg * 8);
    unsigned long long va0 = (unsigned long long)(Vt + bhh * DH * SEQ +
                                                  (size_t)lr * SEQ + lg * 8);
    unsigned long long va1 = va0 + (size_t)16 * SEQ * 2;

    f32x4 acc0 = {}, acc1 = {};
    float mrun = -1e30f, lsum = 0.f;

    // prologue: issue K(0)
    half8 kA[4], kB[4];
    asm volatile(
        "global_load_dwordx4 %0, %[ka], off\n\t"
        "global_load_dwordx4 %1, %[ka], off offset:1024\n\t"
        "global_load_dwordx4 %2, %[ka], off offset:2048\n\t"
        "global_load_dwordx4 %3, %[ka], off offset:3072"
        : "=&v"(kA[0]), "=&v"(kA[1]), "=&v"(kA[2]), "=&v"(kA[3])
        : [ka]"v"(ka));
    ka += 4096;

    for (int t = 0; t < SEQ / 64; t += 2) {
        attn_tile(kA, kB, ka, pa, va0, va1, aq, qaug, xw,
                  mrun, lsum, acc0, acc1, lane, lg);
        attn_tile(kB, kA, ka, pa, va0, va1, aq, qaug, xw,
                  mrun, lsum, acc0, acc1, lane, lg);
    }
    asm volatile("s_waitcnt vmcnt(0)");   // drain the wrap-around prefetch

    // ---- epilogue
    lsum += __shfl_xor(lsum, 16, 64);
    lsum += __shfl_xor(lsum, 32, 64);
    const float inv = 1.f / lsum;                    // lane layout i=lr
    if (lane < 16) xw[lane] = inv;
    f32x4 i4 = *reinterpret_cast<const f32x4*>(&xw[lg * 4]);
#pragma unroll
    for (int t = 0; t < 4; ++t) {
        const size_t row = (size_t)(b * SEQ + i0 + lg * 4 + t) * HID + h * DH;
        AO[row + lr]      = (_Float16)(acc0[t] * i4[t]);
        AO[row + 16 + lr] = (_Float16)(acc1[t] * i4[t]);
    }
}

// ---------------------------------------------------------------- out proj
__global__ __launch_bounds__(256) void out_proj(
    const _Float16* __restrict__ AO, const _Float16* __restrict__ Woh,
    const float* __restrict__ bo, float* __restrict__ out)
{
    const int m0  = blockIdx.x * 64;
    const int n0  = blockIdx.y * 64;
    const int tid = threadIdx.x;
    const int w   = tid >> 6, lane = tid & 63;
    const int lr  = lane & 15, lg = lane >> 4;
    const int wr  = (w >> 1) * 32, wc = (w & 1) * 32;

    f32x4 acc[2][2] = {};
    const int ar = m0 + wr + lr;
    const int br = n0 + wc + lr;
#pragma unroll
    for (int ks = 0; ks < 8; ++ks) {
        const int ko = ks * 32 + lg * 8;
        half8 a0 = *reinterpret_cast<const half8*>(AO + (size_t)ar * HID + ko);
        half8 a1 = *reinterpret_cast<const half8*>(AO + (size_t)(ar + 16) * HID + ko);
        half8 b0 = *reinterpret_cast<const half8*>(Woh + (size_t)br * HID + ko);
        half8 b1 = *reinterpret_cast<const half8*>(Woh + (size_t)(br + 16) * HID + ko);
        acc[0][0] = __builtin_amdgcn_mfma_f32_16x16x32_f16(a0, b0, acc[0][0], 0, 0, 0);
        acc[0][1] = __builtin_amdgcn_mfma_f32_16x16x32_f16(a0, b1, acc[0][1], 0, 0, 0);
        acc[1][0] = __builtin_amdgcn_mfma_f32_16x16x32_f16(a1, b0, acc[1][0], 0, 0, 0);
        acc[1][1] = __builtin_amdgcn_mfma_f32_16x16x32_f16(a1, b1, acc[1][1], 0, 0, 0);
    }
#pragma unroll
    for (int mf = 0; mf < 2; ++mf)
#pragma unroll
    for (int nf = 0; nf < 2; ++nf)
#pragma unroll
    for (int r = 0; r < 4; ++r) {
        const int m = m0 + wr + mf * 16 + lg * 4 + r;
        const int o = n0 + wc + nf * 16 + lr;
        out[(size_t)m * HID + o] = acc[mf][nf][r] + bo[o];
    }
}

// ---------------------------------------------------------------- launch
extern "C" void kernel_launch(void* const* d_in, const int* in_sizes, int n_in,
                              void* d_out, int out_size, void* d_ws, size_t ws_size,
                              hipStream_t stream)
{
    const float* x   = (const float*)d_in[0];
    const float* pos = (const float*)d_in[1];
    const float* Wq  = (const float*)d_in[2];
    const float* bq  = (const float*)d_in[3];
    const float* Wk  = (const float*)d_in[4];
    const float* bk  = (const float*)d_in[5];
    const float* Wv  = (const float*)d_in[6];
    const float* bv  = (const float*)d_in[7];
    const float* Wo  = (const float*)d_in[8];
    const float* bo  = (const float*)d_in[9];
    float* out = (float*)d_out;

    char* ws = (char*)d_ws;
    _Float16* Qh = (_Float16*)(ws);                 // 4 MB
    _Float16* Kh = (_Float16*)(ws + (4  << 20));    // 4 MB
    _Float16* Vt = (_Float16*)(ws + (8  << 20));    // 4 MB
    _Float16* xh = (_Float16*)(ws + (12 << 20));    // 4 MB (reused as AO)
    _Float16* AO = xh;                              // safe: attn runs after qkv_proj
    _Float16* Wh = (_Float16*)(ws + (16 << 20));    // 512 KB
    _Float16* Pg = (_Float16*)(ws + (16 << 20) + (512 << 10)); // 512 KB + pad

    const int NX = BATCH * SEQ * HID;               // 2,097,152
    const int NW = HID * HID;                       // 65,536
    cvt_f32_f16<<<NX / 1024, 256, 0, stream>>>(x, xh, NX);
    cvt_w4<<<dim3(NW / 1024, 4), 256, 0, stream>>>(Wq, Wk, Wv, Wo, Wh);
    paug_kernel<<<BATCH * SEQ / 256, 256, 0, stream>>>(pos, Pg);

    qkv_proj<<<dim3(BATCH * SEQ / 64, HID / 64, 3), 256, 0, stream>>>(
        xh, Wh, bq, bk, bv, Qh, Kh, Vt);

    attn_kernel<<<BATCH * NHEAD * (SEQ / 16), 64, 0, stream>>>(
        Qh, Kh, Vt, Pg, pos, AO);

    out_proj<<<dim3(BATCH * SEQ / 64, HID / 64), 256, 0, stream>>>(
        AO, Wh + 3 * NW, bo, out);
}

// Round 10
// 236.421 us; speedup vs baseline: 1.2372x; 1.2372x over previous
//
#include <hip/hip_runtime.h>

#define BATCH 2
#define SEQ   4096
#define HID   256
#define NHEAD 8
#define DH    32
// defer-max threshold in log2 units (≈ 8 nats)
#define THR_L2 11.5f
// 1/sqrt(32) * log2(e)
#define QSCALE 0.25501639769925074f
// -(1/10) * log2(e)
#define BIASC (-0.14426950408889634f)

typedef __attribute__((ext_vector_type(8))) _Float16 half8;
typedef __attribute__((ext_vector_type(4))) _Float16 half4;
typedef __attribute__((ext_vector_type(2))) __fp16   fp16x2;
typedef __attribute__((ext_vector_type(4))) float    f32x4;
typedef __attribute__((ext_vector_type(4))) unsigned int uint4v;

__device__ __forceinline__ float fast_exp2(float x) {
    return __builtin_amdgcn_exp2f(x);
}

// ---------------------------------------------------------------- convert
__global__ void cvt_f32_f16(const float* __restrict__ src,
                            _Float16* __restrict__ dst, int n) {
    int i = (blockIdx.x * blockDim.x + threadIdx.x) * 4;
    if (i >= n) return;
    f32x4 v = *reinterpret_cast<const f32x4*>(src + i);
    half4 h;
#pragma unroll
    for (int c = 0; c < 4; ++c) h[c] = (_Float16)v[c];
    *reinterpret_cast<half4*>(dst + i) = h;
}

__global__ void cvt_w4(const float* __restrict__ a, const float* __restrict__ b,
                       const float* __restrict__ c, const float* __restrict__ d,
                       _Float16* __restrict__ dst) {
    const float* srcs[4] = {a, b, c, d};
    const float* s = srcs[blockIdx.y];
    const int i = (blockIdx.x * blockDim.x + threadIdx.x) * 4;
    f32x4 v = *reinterpret_cast<const f32x4*>(s + i);
    half4 h;
#pragma unroll
    for (int k = 0; k < 4; ++k) h[k] = (_Float16)v[k];
    *reinterpret_cast<half4*>(dst + (size_t)blockIdx.y * HID * HID + i) = h;
}

// ---------------------------------------------------------------- QKV proj
// V stored transposed [B][H][DH][SEQ] with a within-32 column permutation so
// that the QK^T output fragment, packed pairwise, is directly the PV
// A-fragment: col = (nn&~31) | ((nn&12)<<1) | ((nn&16)>>2) | (nn&3)
__global__ __launch_bounds__(256) void qkv_proj(
    const _Float16* __restrict__ xh, const _Float16* __restrict__ Wh,
    const float* __restrict__ bq, const float* __restrict__ bk,
    const float* __restrict__ bv,
    _Float16* __restrict__ Qh, _Float16* __restrict__ Kh,
    _Float16* __restrict__ Vt)
{
    const int z   = blockIdx.z;
    const int m0  = blockIdx.x * 64;
    const int n0  = blockIdx.y * 64;
    const int tid = threadIdx.x;
    const int w   = tid >> 6, lane = tid & 63;
    const int lr  = lane & 15, lg = lane >> 4;
    const int wr  = (w >> 1) * 32, wc = (w & 1) * 32;

    const _Float16* Wp = Wh + (size_t)z * HID * HID;
    const float* bias = (z == 0) ? bq : (z == 1) ? bk : bv;

    f32x4 acc[2][2] = {};
    const int ar = m0 + wr + lr;
    const int br = n0 + wc + lr;
#pragma unroll
    for (int ks = 0; ks < 8; ++ks) {
        const int ko = ks * 32 + lg * 8;
        half8 a0 = *reinterpret_cast<const half8*>(xh + (size_t)ar * HID + ko);
        half8 a1 = *reinterpret_cast<const half8*>(xh + (size_t)(ar + 16) * HID + ko);
        half8 b0 = *reinterpret_cast<const half8*>(Wp + (size_t)br * HID + ko);
        half8 b1 = *reinterpret_cast<const half8*>(Wp + (size_t)(br + 16) * HID + ko);
        acc[0][0] = __builtin_amdgcn_mfma_f32_16x16x32_f16(a0, b0, acc[0][0], 0, 0, 0);
        acc[0][1] = __builtin_amdgcn_mfma_f32_16x16x32_f16(a0, b1, acc[0][1], 0, 0, 0);
        acc[1][0] = __builtin_amdgcn_mfma_f32_16x16x32_f16(a1, b0, acc[1][0], 0, 0, 0);
        acc[1][1] = __builtin_amdgcn_mfma_f32_16x16x32_f16(a1, b1, acc[1][1], 0, 0, 0);
    }
#pragma unroll
    for (int mf = 0; mf < 2; ++mf)
#pragma unroll
    for (int nf = 0; nf < 2; ++nf)
#pragma unroll
    for (int r = 0; r < 4; ++r) {
        const int m  = m0 + wr + mf * 16 + lg * 4 + r;
        const int o  = n0 + wc + nf * 16 + lr;
        const int bb = m >> 12, nn = m & (SEQ - 1);
        const int hh = o >> 5,  dd = o & (DH - 1);
        float v = acc[mf][nf][r] + bias[o];
        if (z == 0) {
            Qh[(((size_t)(bb * NHEAD + hh) * SEQ) + nn) * DH + dd] =
                (_Float16)(v * QSCALE);
        } else if (z == 1) {
            Kh[(((size_t)(bb * NHEAD + hh) * SEQ) + nn) * DH + dd] = (_Float16)v;
        } else {
            const int pp = (nn & ~31) | ((nn & 12) << 1) | ((nn & 16) >> 2) | (nn & 3);
            Vt[(((size_t)(bb * NHEAD + hh) * DH) + dd) * SEQ + pp] = (_Float16)v;
        }
    }
}

// ---------------------------------------------------------------- attention
// One 64-key tile with counted-vmcnt register pipeline. Entering pending:
// K(t)[4]. Issue V(t)[4] + K(t+1)[4] -> 12 outstanding.
// vmcnt(8): K(t) ready -> QK^T (bias from LDS rides C). vmcnt(4): V(t)
// ready -> PV. K(t+1) stays in flight across the tile boundary.
__device__ __forceinline__ void attn_tile(
    int s, half8 (&kc)[4], half8 (&kn)[4],
    unsigned long long& ka, unsigned long long& va0, unsigned long long& va1,
    half8 aq, const float* __restrict__ biasRow, float* xw,
    float& mrun, float& lsum, f32x4& acc0, f32x4& acc1, int lane, int lg)
{
    half8 vc0, vc1, vc2, vc3;
    asm volatile(
        "global_load_dwordx4 %0, %[va0], off\n\t"
        "global_load_dwordx4 %1, %[va1], off\n\t"
        "global_load_dwordx4 %2, %[va0], off offset:64\n\t"
        "global_load_dwordx4 %3, %[va1], off offset:64\n\t"
        "global_load_dwordx4 %4, %[ka], off\n\t"
        "global_load_dwordx4 %5, %[ka], off offset:1024\n\t"
        "global_load_dwordx4 %6, %[ka], off offset:2048\n\t"
        "global_load_dwordx4 %7, %[ka], off offset:3072"
        : "=&v"(vc0), "=&v"(vc1), "=&v"(vc2), "=&v"(vc3),
          "=&v"(kn[0]), "=&v"(kn[1]), "=&v"(kn[2]), "=&v"(kn[3])
        : [va0]"v"(va0), [va1]"v"(va1), [ka]"v"(ka));
    va0 += 128; va1 += 128; ka += 4096;

    // ---- K(t) ready
    asm volatile("s_waitcnt vmcnt(8)");
    __builtin_amdgcn_sched_barrier(0);
    f32x4 vv[4];
    __builtin_amdgcn_s_setprio(1);
#pragma unroll
    for (int cf = 0; cf < 4; ++cf) {
        f32x4 cb = *reinterpret_cast<const f32x4*>(
            biasRow + s * 64 + cf * 16 + lg * 4);
        vv[cf] = __builtin_amdgcn_mfma_f32_16x16x32_f16(kc[cf], aq, cb, 0, 0, 0);
    }
    __builtin_amdgcn_s_setprio(0);

    // ---- lane-local defer-max online softmax (log2 domain)
    float m0 = fmaxf(fmaxf(vv[0][0], vv[0][1]), vv[0][2]);
    float m1 = fmaxf(fmaxf(vv[0][3], vv[1][0]), vv[1][1]);
    float m2 = fmaxf(fmaxf(vv[1][2], vv[1][3]), vv[2][0]);
    float m3 = fmaxf(fmaxf(vv[2][1], vv[2][2]), vv[2][3]);
    float m4 = fmaxf(fmaxf(vv[3][0], vv[3][1]), vv[3][2]);
    float tmax = fmaxf(fmaxf(fmaxf(m0, m1), fmaxf(m2, m3)),
                       fmaxf(m4, vv[3][3]));

    if (!__all(tmax <= mrun + THR_L2)) {     // rare rescale path (wave-uniform)
        float tm = tmax;
        tm = fmaxf(tm, __shfl_xor(tm, 16, 64));
        tm = fmaxf(tm, __shfl_xor(tm, 32, 64));
        const float mnew  = fmaxf(mrun, tm);
        const float alpha = fast_exp2(mrun - mnew);
        if (lane < 16) xw[lane] = alpha;
        f32x4 a4 = *reinterpret_cast<const f32x4*>(&xw[lg * 4]);
        lsum *= alpha;
        mrun = mnew;
        acc0 *= a4;
        acc1 *= a4;
    }

    // ---- exp2 + pairwise pack straight into the PV A-fragments
    float e00 = fast_exp2(vv[0][0] - mrun), e01 = fast_exp2(vv[0][1] - mrun);
    float e02 = fast_exp2(vv[0][2] - mrun), e03 = fast_exp2(vv[0][3] - mrun);
    float e10 = fast_exp2(vv[1][0] - mrun), e11 = fast_exp2(vv[1][1] - mrun);
    float e12 = fast_exp2(vv[1][2] - mrun), e13 = fast_exp2(vv[1][3] - mrun);
    float e20 = fast_exp2(vv[2][0] - mrun), e21 = fast_exp2(vv[2][1] - mrun);
    float e22 = fast_exp2(vv[2][2] - mrun), e23 = fast_exp2(vv[2][3] - mrun);
    float e30 = fast_exp2(vv[3][0] - mrun), e31 = fast_exp2(vv[3][1] - mrun);
    float e32 = fast_exp2(vv[3][2] - mrun), e33 = fast_exp2(vv[3][3] - mrun);
    lsum += ((e00 + e01) + (e02 + e03)) + ((e10 + e11) + (e12 + e13)) +
            ((e20 + e21) + (e22 + e23)) + ((e30 + e31) + (e32 + e33));

    uint4v u0, u1;
    u0[0] = __builtin_bit_cast(unsigned int, __builtin_amdgcn_cvt_pkrtz(e00, e01));
    u0[1] = __builtin_bit_cast(unsigned int, __builtin_amdgcn_cvt_pkrtz(e02, e03));
    u0[2] = __builtin_bit_cast(unsigned int, __builtin_amdgcn_cvt_pkrtz(e10, e11));
    u0[3] = __builtin_bit_cast(unsigned int, __builtin_amdgcn_cvt_pkrtz(e12, e13));
    u1[0] = __builtin_bit_cast(unsigned int, __builtin_amdgcn_cvt_pkrtz(e20, e21));
    u1[1] = __builtin_bit_cast(unsigned int, __builtin_amdgcn_cvt_pkrtz(e22, e23));
    u1[2] = __builtin_bit_cast(unsigned int, __builtin_amdgcn_cvt_pkrtz(e30, e31));
    u1[3] = __builtin_bit_cast(unsigned int, __builtin_amdgcn_cvt_pkrtz(e32, e33));
    half8 pa0 = __builtin_bit_cast(half8, u0);
    half8 pa1 = __builtin_bit_cast(half8, u1);

    // ---- V(t) ready -> PV (V cols pre-permuted to match the pack)
    asm volatile("s_waitcnt vmcnt(4)");
    __builtin_amdgcn_sched_barrier(0);
    __builtin_amdgcn_s_setprio(1);
    acc0 = __builtin_amdgcn_mfma_f32_16x16x32_f16(pa0, vc0, acc0, 0, 0, 0);
    acc1 = __builtin_amdgcn_mfma_f32_16x16x32_f16(pa0, vc1, acc1, 0, 0, 0);
    acc0 = __builtin_amdgcn_mfma_f32_16x16x32_f16(pa1, vc2, acc0, 0, 0, 0);
    acc1 = __builtin_amdgcn_mfma_f32_16x16x32_f16(pa1, vc3, acc1, 0, 0, 0);
    __builtin_amdgcn_s_setprio(0);
}

// grid = 512 1D blocks, 512 threads = 8 waves = 8 heads, i-tile 16 rows.
// XCD-batch swizzle: x = g&7 (XCD under round-robin), b = x>>2 so each XCD
// serves ONE batch's 8 K/V streams (4 MB, L2-resident). iblk = (g>>3)*4+(x&3).
__global__ __launch_bounds__(512, 4) void attn_kernel(
    const _Float16* __restrict__ Qh, const _Float16* __restrict__ Kh,
    const _Float16* __restrict__ Vt, const float* __restrict__ pos,
    _Float16* __restrict__ AO)
{
    __shared__ __align__(16) float pi4[16][4];
    __shared__ __align__(16) float pj4[512][4];
    __shared__ __align__(16) float biasL[16][516];   // 33 KB
    __shared__ __align__(16) float xposeL[NHEAD][16];

    const int g    = blockIdx.x;
    const int x    = g & 7;
    const int b    = x >> 2;
    const int i0   = ((g >> 3) * 4 + (x & 3)) * 16;
    const int tid  = threadIdx.x;
    const int w    = tid >> 6;           // head
    const int lane = tid & 63;
    const int lr   = lane & 15, lg = lane >> 4;

    if (tid < 16) {
        const float* p = pos + (size_t)(b * SEQ + i0 + tid) * 3;
        float xx = p[0], yy = p[1], zz = p[2];
        pi4[tid][0] = xx; pi4[tid][1] = yy; pi4[tid][2] = zz;
        pi4[tid][3] = xx * xx + yy * yy + zz * zz;
    }

    const size_t bhh = (size_t)(b * NHEAD + w);
    const half8 aq = *reinterpret_cast<const half8*>(
        Qh + (bhh * SEQ + i0 + lr) * DH + lg * 8);

    unsigned long long ka  = (unsigned long long)(Kh + bhh * SEQ * DH +
                                                  (size_t)lr * DH + lg * 8);
    unsigned long long va0 = (unsigned long long)(Vt + bhh * DH * SEQ +
                                                  (size_t)lr * SEQ + lg * 8);
    unsigned long long va1 = va0 + (size_t)16 * SEQ * 2;

    f32x4 acc0 = {}, acc1 = {};
    float mrun = -1e30f, lsum = 0.f;

    float* xw = &xposeL[w][0];
    const float* biasRow = &biasL[lr][0];

    // prologue: issue K(0)
    half8 kA[4], kB[4];
    asm volatile(
        "global_load_dwordx4 %0, %[ka], off\n\t"
        "global_load_dwordx4 %1, %[ka], off offset:1024\n\t"
        "global_load_dwordx4 %2, %[ka], off offset:2048\n\t"
        "global_load_dwordx4 %3, %[ka], off offset:3072"
        : "=&v"(kA[0]), "=&v"(kA[1]), "=&v"(kA[2]), "=&v"(kA[3])
        : [ka]"v"(ka));
    ka += 4096;

    for (int ch = 0; ch < SEQ / 512; ++ch) {
        __syncthreads();                       // protect pj4/biasL from prev chunk readers
        {
            const float* p = pos + (size_t)(b * SEQ + ch * 512 + tid) * 3;
            float xx = p[0], yy = p[1], zz = p[2];
            pj4[tid][0] = xx; pj4[tid][1] = yy; pj4[tid][2] = zz;
            pj4[tid][3] = xx * xx + yy * yy + zz * zz;
        }
        __syncthreads();
        {   // bias tile 16 x 512: 16 values per thread, b128 stores
            const int br  = tid & 15;
            const int c0  = (tid >> 4) * 16;
            const float xi = pi4[br][0], yi = pi4[br][1], zi = pi4[br][2], si = pi4[br][3];
#pragma unroll
            for (int k4 = 0; k4 < 4; ++k4) {
                f32x4 o;
#pragma unroll
                for (int k = 0; k < 4; ++k) {
                    const float* pj = &pj4[c0 + k4 * 4 + k][0];
                    float dot = xi * pj[0] + yi * pj[1] + zi * pj[2];
                    float d2  = si + pj[3] - 2.f * dot;
                    o[k] = BIASC * sqrtf(fmaxf(d2, 0.f));
                }
                *reinterpret_cast<f32x4*>(&biasL[br][c0 + k4 * 4]) = o;
            }
        }
        __syncthreads();

        for (int s = 0; s < 4; ++s) {
            attn_tile(2 * s,     kA, kB, ka, va0, va1, aq, biasRow, xw,
                      mrun, lsum, acc0, acc1, lane, lg);
            attn_tile(2 * s + 1, kB, kA, ka, va0, va1, aq, biasRow, xw,
                      mrun, lsum, acc0, acc1, lane, lg);
        }
    }
    asm volatile("s_waitcnt vmcnt(0)");   // drain the overhang K prefetch

    // ---- epilogue
    lsum += __shfl_xor(lsum, 16, 64);
    lsum += __shfl_xor(lsum, 32, 64);
    const float inv = 1.f / lsum;                    // lane layout i=lr
    if (lane < 16) xw[lane] = inv;
    f32x4 i4 = *reinterpret_cast<const f32x4*>(&xw[lg * 4]);
#pragma unroll
    for (int t = 0; t < 4; ++t) {
        const size_t row = (size_t)(b * SEQ + i0 + lg * 4 + t) * HID + w * DH;
        AO[row + lr]      = (_Float16)(acc0[t] * i4[t]);
        AO[row + 16 + lr] = (_Float16)(acc1[t] * i4[t]);
    }
}

// ---------------------------------------------------------------- out proj
__global__ __launch_bounds__(256) void out_proj(
    const _Float16* __restrict__ AO, const _Float16* __restrict__ Woh,
    const float* __restrict__ bo, float* __restrict__ out)
{
    const int m0  = blockIdx.x * 64;
    const int n0  = blockIdx.y * 64;
    const int tid = threadIdx.x;
    const int w   = tid >> 6, lane = tid & 63;
    const int lr  = lane & 15, lg = lane >> 4;
    const int wr  = (w >> 1) * 32, wc = (w & 1) * 32;

    f32x4 acc[2][2] = {};
    const int ar = m0 + wr + lr;
    const int br = n0 + wc + lr;
#pragma unroll
    for (int ks = 0; ks < 8; ++ks) {
        const int ko = ks * 32 + lg * 8;
        half8 a0 = *reinterpret_cast<const half8*>(AO + (size_t)ar * HID + ko);
        half8 a1 = *reinterpret_cast<const half8*>(AO + (size_t)(ar + 16) * HID + ko);
        half8 b0 = *reinterpret_cast<const half8*>(Woh + (size_t)br * HID + ko);
        half8 b1 = *reinterpret_cast<const half8*>(Woh + (size_t)(br + 16) * HID + ko);
        acc[0][0] = __builtin_amdgcn_mfma_f32_16x16x32_f16(a0, b0, acc[0][0], 0, 0, 0);
        acc[0][1] = __builtin_amdgcn_mfma_f32_16x16x32_f16(a0, b1, acc[0][1], 0, 0, 0);
        acc[1][0] = __builtin_amdgcn_mfma_f32_16x16x32_f16(a1, b0, acc[1][0], 0, 0, 0);
        acc[1][1] = __builtin_amdgcn_mfma_f32_16x16x32_f16(a1, b1, acc[1][1], 0, 0, 0);
    }
#pragma unroll
    for (int mf = 0; mf < 2; ++mf)
#pragma unroll
    for (int nf = 0; nf < 2; ++nf)
#pragma unroll
    for (int r = 0; r < 4; ++r) {
        const int m = m0 + wr + mf * 16 + lg * 4 + r;
        const int o = n0 + wc + nf * 16 + lr;
        out[(size_t)m * HID + o] = acc[mf][nf][r] + bo[o];
    }
}

// ---------------------------------------------------------------- launch
extern "C" void kernel_launch(void* const* d_in, const int* in_sizes, int n_in,
                              void* d_out, int out_size, void* d_ws, size_t ws_size,
                              hipStream_t stream)
{
    const float* x   = (const float*)d_in[0];
    const float* pos = (const float*)d_in[1];
    const float* Wq  = (const float*)d_in[2];
    const float* bq  = (const float*)d_in[3];
    const float* Wk  = (const float*)d_in[4];
    const float* bk  = (const float*)d_in[5];
    const float* Wv  = (const float*)d_in[6];
    const float* bv  = (const float*)d_in[7];
    const float* Wo  = (const float*)d_in[8];
    const float* bo  = (const float*)d_in[9];
    float* out = (float*)d_out;

    char* ws = (char*)d_ws;
    _Float16* Qh = (_Float16*)(ws);                 // 4 MB
    _Float16* Kh = (_Float16*)(ws + (4  << 20));    // 4 MB
    _Float16* Vt = (_Float16*)(ws + (8  << 20));    // 4 MB
    _Float16* xh = (_Float16*)(ws + (12 << 20));    // 4 MB (reused as AO)
    _Float16* AO = xh;                              // safe: attn runs after qkv_proj
    _Float16* Wh = (_Float16*)(ws + (16 << 20));    // 512 KB

    const int NX = BATCH * SEQ * HID;               // 2,097,152
    const int NW = HID * HID;                       // 65,536
    cvt_f32_f16<<<NX / 1024, 256, 0, stream>>>(x, xh, NX);
    cvt_w4<<<dim3(NW / 1024, 4), 256, 0, stream>>>(Wq, Wk, Wv, Wo, Wh);

    qkv_proj<<<dim3(BATCH * SEQ / 64, HID / 64, 3), 256, 0, stream>>>(
        xh, Wh, bq, bk, bv, Qh, Kh, Vt);

    attn_kernel<<<512, 512, 0, stream>>>(Qh, Kh, Vt, pos, AO);

    out_proj<<<dim3(BATCH * SEQ / 64, HID / 64), 256, 0, stream>>>(
        AO, Wh + 3 * NW, bo, out);
}